// Round 4
// baseline (321.979 us; speedup 1.0000x reference)
//
#include <hip/hip_runtime.h>

typedef unsigned int u32;
typedef __fp16 half2_t __attribute__((ext_vector_type(2)));
typedef __fp16 half8_t __attribute__((ext_vector_type(8)));
typedef float  f32x4   __attribute__((ext_vector_type(4)));

#define DIN 128
#define DH  128
#define SEQL 512
#define NBATCH 256
#define NC  512          // 4*DH fused gate columns
#define TC  64           // timesteps per chunk
#define NCHUNK (SEQL/TC) // 8

#define LDS_HOFF 65536   // hbuf byte offset (xgT = 64 KB below it)
#define LDS_TOTAL (65536 + 512)

__device__ __forceinline__ u32 pk2(float a, float b) {
  half2_t h = __builtin_amdgcn_cvt_pkrtz(a, b);
  return __builtin_bit_cast(u32, h);
}

__device__ __forceinline__ float dot2(u32 a, u32 b, float c) {
#if defined(__has_builtin) && __has_builtin(__builtin_amdgcn_fdot2)
  return __builtin_amdgcn_fdot2(__builtin_bit_cast(half2_t, a),
                                __builtin_bit_cast(half2_t, b), c, false);
#else
  half2_t ha = __builtin_bit_cast(half2_t, a);
  half2_t hb = __builtin_bit_cast(half2_t, b);
  return c + (float)ha[0]*(float)hb[0] + (float)ha[1]*(float)hb[1];
#endif
}

#if defined(__has_builtin) && __has_builtin(__builtin_amdgcn_update_dpp)
__device__ __forceinline__ float qp_xor1(float v) {   // quad_perm [1,0,3,2]
  return __builtin_bit_cast(float,
      __builtin_amdgcn_update_dpp(0, __builtin_bit_cast(int, v), 0xB1, 0xF, 0xF, true));
}
__device__ __forceinline__ float qp_xor2(float v) {   // quad_perm [2,3,0,1]
  return __builtin_bit_cast(float,
      __builtin_amdgcn_update_dpp(0, __builtin_bit_cast(int, v), 0x4E, 0xF, 0xF, true));
}
template <int CTRL>
__device__ __forceinline__ float qbc(float v) {       // quad broadcast lane CTRL pattern
  return __builtin_bit_cast(float,
      __builtin_amdgcn_update_dpp(0, __builtin_bit_cast(int, v), CTRL, 0xF, 0xF, true));
}
#else
__device__ __forceinline__ float qp_xor1(float v) { return __shfl_xor(v, 1, 64); }
__device__ __forceinline__ float qp_xor2(float v) { return __shfl_xor(v, 2, 64); }
template <int CTRL>
__device__ __forceinline__ float qbc(float v) {
  return __shfl(v, (threadIdx.x & ~3) + (CTRL & 3), 64);
}
#endif

__device__ __forceinline__ float fexp2(float x) {
#if defined(__has_builtin) && __has_builtin(__builtin_amdgcn_exp2f)
  return __builtin_amdgcn_exp2f(x);
#else
  return __builtin_exp2f(x);
#endif
}

// 8 dot2s: one per accumulator chain (dep distance 8 instructions)
#define D8(C, MA, HA, MB, HB) \
  pa0 = dot2(wq[0][MA].C, (HA).C, pa0); \
  pa1 = dot2(wq[1][MA].C, (HA).C, pa1); \
  pa2 = dot2(wq[2][MA].C, (HA).C, pa2); \
  pa3 = dot2(wq[3][MA].C, (HA).C, pa3); \
  pb0 = dot2(wq[0][MB].C, (HB).C, pb0); \
  pb1 = dot2(wq[1][MB].C, (HB).C, pb1); \
  pb2 = dot2(wq[2][MB].C, (HB).C, pb2); \
  pb3 = dot2(wq[3][MB].C, (HB).C, pb3);

// Pack fused weight matrices into f16-pair (k-pair) column-major images:
// wxT[j][kk] = (wx[2kk][j], wx[2kk+1][j]),  j in [0,512), kk in [0,64)
__global__ void pack_w(const float* __restrict__ x2i, const float* __restrict__ x2f,
                       const float* __restrict__ x2g, const float* __restrict__ x2o,
                       const float* __restrict__ h2i, const float* __restrict__ h2f,
                       const float* __restrict__ h2g, const float* __restrict__ h2o,
                       u32* __restrict__ wxT, u32* __restrict__ whT) {
  int idx = blockIdx.x * blockDim.x + threadIdx.x;   // 0..32767
  if (idx >= NC * 64) return;
  int j = idx >> 6, kk = idx & 63;
  int g = j >> 7, jjj = j & 127;
  const float* wx = (g == 0) ? x2i : (g == 1) ? x2f : (g == 2) ? x2g : x2o;
  const float* wh = (g == 0) ? h2i : (g == 1) ? h2f : (g == 2) ? h2g : h2o;
  wxT[idx] = pk2(wx[(2*kk)*DH + jjj], wx[(2*kk+1)*DH + jjj]);
  whT[idx] = pk2(wh[(2*kk)*DH + jjj], wh[(2*kk+1)*DH + jjj]);
}

// LDS: xgT [512 col][128 B of t, XOR-swizzled f16] = 64 KB ; hbuf [2][64] u32
__global__ __launch_bounds__(512)
__attribute__((amdgpu_waves_per_eu(2, 2)))
void lstm_fused(
    const float* __restrict__ x, const u32* __restrict__ wxT,
    const u32* __restrict__ whT, const float* __restrict__ w_out,
    float* __restrict__ out) {
  extern __shared__ char lds[];
  char* xgT  = lds;
  u32*  hbuf = (u32*)(lds + LDS_HOFF);

  const int tid = threadIdx.x;
  const int b   = blockIdx.x;
  const int l   = tid & 63, wv = tid >> 6;
  // phase-B coords: quad member kq = gate id AND k-quarter; jj hidden-offset
  const int kq  = l & 3, jj = l >> 2;
  const int colB = kq * DH + wv * 16 + jj;   // this lane's xg gate-column
  const int j    = wv * 16 + jj;             // hidden index owned by quad
  // phase-A coords
  const int kg = l >> 4, r15 = l & 15;

  // phase-B weights: wq[q][mm] = whT[q*128 + j][16*kq + mm*4 .. +4]  (64 VGPRs)
  uint4 wq[4][4];
#pragma unroll
  for (int q = 0; q < 4; ++q) {
    const uint4* wp = (const uint4*)(whT + (q * DH + j) * 64 + kq * 16);
#pragma unroll
    for (int mm = 0; mm < 4; ++mm) wq[q][mm] = wp[mm];
  }

  if (tid < 128) hbuf[tid] = 0u;   // zero both h buffers
  float c = 0.f;
  u32 rdoff = LDS_HOFF + kq * 64;        // read h buf 0 first
  u32 wroff = LDS_HOFF + 256 + j * 2;    // write h buf 1 first
  const bool k1 = (kq & 1) != 0, k2 = (kq & 2) != 0;
  const bool isG = (kq == 2);
  const float mexp = isG ? -2.885390082f : -1.442695041f;  // exp2 multipliers
  const float cA = isG ? 2.f : 1.f;
  const float cB = isG ? -1.f : 0.f;

  const float* xb = x + (size_t)b * SEQL * DIN;
  __syncthreads();

  for (int ch = 0; ch < NCHUNK; ++ch) {
    // ---- phase A: xg[t][col] = x_chunk @ wx via MFMA, A-frags from global ----
#pragma unroll 1
    for (int tt = 0; tt < 4; ++tt) {
      uint4 afr[4];
#pragma unroll
      for (int ko = 0; ko < 4; ++ko) {
        const float4* xp = (const float4*)(xb + (size_t)(ch*TC + tt*16 + r15)*DIN + ko*32 + kg*8);
        float4 v0 = xp[0], v1 = xp[1];
        afr[ko].x = pk2(v0.x, v0.y); afr[ko].y = pk2(v0.z, v0.w);
        afr[ko].z = pk2(v1.x, v1.y); afr[ko].w = pk2(v1.z, v1.w);
      }
#pragma unroll
      for (int nt = 0; nt < 4; ++nt) {
        int n = wv * 64 + nt * 16 + r15;
        f32x4 acc = {0.f, 0.f, 0.f, 0.f};
#pragma unroll
        for (int ko = 0; ko < 4; ++ko) {
          uint4 bf = *(const uint4*)(wxT + n*64 + ko*16 + kg*4);
          acc = __builtin_amdgcn_mfma_f32_16x16x32_f16(
              __builtin_bit_cast(half8_t, afr[ko]),
              __builtin_bit_cast(half8_t, bf), acc, 0, 0, 0);
        }
        // store C: col n, t0 = tt*16+kg*4 .. +4, into [col][t] XOR-swizzled
        int t0 = tt*16 + kg*4;
        u32 off = (u32)(n*128 + ((t0*2) ^ ((n & 7) << 4)));
        uint2 pw; pw.x = pk2(acc[0], acc[1]); pw.y = pk2(acc[2], acc[3]);
        *(uint2*)(xgT + off) = pw;
      }
    }
    __syncthreads();

    // ---- phase B: 64 sequential steps, k-split=4 over DPP quads ----
#pragma unroll 1
    for (int m = 0; m < 8; ++m) {
      uint4 xgv = *(const uint4*)(xgT + colB*128 + ((m*16) ^ ((colB & 7) << 4)));
      half8_t xgh = __builtin_bit_cast(half8_t, xgv);
      float xf[8];
#pragma unroll
      for (int i = 0; i < 8; ++i) xf[i] = (float)xgh[i];
#pragma unroll
      for (int s8 = 0; s8 < 8; ++s8) {
        uint4 h0 = *(const uint4*)(lds + rdoff);
        uint4 h1 = *(const uint4*)(lds + rdoff + 16);
        uint4 h2 = *(const uint4*)(lds + rdoff + 32);
        uint4 h3 = *(const uint4*)(lds + rdoff + 48);
        float pa0 = 0.f, pa1 = 0.f, pa2 = 0.f, pa3 = 0.f;
        float pb0 = 0.f, pb1 = 0.f, pb2 = 0.f, pb3 = 0.f;
        D8(x, 0, h0, 2, h2) D8(y, 0, h0, 2, h2)
        D8(z, 0, h0, 2, h2) D8(w, 0, h0, 2, h2)
        D8(x, 1, h1, 3, h3) D8(y, 1, h1, 3, h3)
        D8(z, 1, h1, 3, h3) D8(w, 1, h1, 3, h3)
        float m0 = pa0 + pb0, m1 = pa1 + pb1, m2 = pa2 + pb2, m3 = pa3 + pb3;
        // quad transpose-reduce: lane kq ends with full sum of gate kq
        float uA = k1 ? m1 : m0, vA = k1 ? m0 : m1;
        float uB = k1 ? m3 : m2, vB = k1 ? m2 : m3;
        uA += qp_xor1(vA);
        uB += qp_xor1(vB);
        float wS = k2 ? uB : uA, gv = k2 ? uA : uB;
        wS += qp_xor2(gv);
        float tk = wS + xf[s8];
        // nonlinearity (sigmoid; tanh for kq==2 via per-lane constants)
        float e   = fexp2(tk * mexp);
        float y   = __builtin_amdgcn_rcpf(1.f + e);
        float val = __builtin_fmaf(cA, y, cB);
        // quad broadcast: (i,f,g,o) to every lane
        float gi = qbc<0x00>(val);
        float gf = qbc<0x55>(val);
        float gg = qbc<0xAA>(val);
        float go = qbc<0xFF>(val);
        c = __builtin_fmaf(gf, c, gi * gg);
        float e2 = fexp2(c * -2.885390082f);
        float th = __builtin_fmaf(2.f, __builtin_amdgcn_rcpf(1.f + e2), -1.f);
        float hval = go * th;
        if (kq == 0) *(__fp16*)(lds + wroff) = (__fp16)hval;
        rdoff ^= 256; wroff ^= 256;
        __syncthreads();
      }
    }
  }

  // ---- tail: out[b][n] = h_final @ w_out ----
  if (tid < DH) {
    int n = tid;
    const u32* hf = (const u32*)(lds + (rdoff & ~(u32)255));  // current h buffer
    float acc = 0.f;
#pragma unroll 8
    for (int kk = 0; kk < 64; ++kk) {
      half2_t h2v = __builtin_bit_cast(half2_t, hf[kk]);
      acc = __builtin_fmaf((float)h2v[0], w_out[(2*kk)*DH + n],
            __builtin_fmaf((float)h2v[1], w_out[(2*kk+1)*DH + n], acc));
    }
    out[b * DH + n] = acc;
  }
}

extern "C" void kernel_launch(void* const* d_in, const int* in_sizes, int n_in,
                              void* d_out, int out_size, void* d_ws, size_t ws_size,
                              hipStream_t stream) {
  const float* x    = (const float*)d_in[0];
  const float* x2i  = (const float*)d_in[1];
  const float* x2f  = (const float*)d_in[2];
  const float* x2g  = (const float*)d_in[3];
  const float* x2o  = (const float*)d_in[4];
  const float* h2i  = (const float*)d_in[5];
  const float* h2f  = (const float*)d_in[6];
  const float* h2g  = (const float*)d_in[7];
  const float* h2o  = (const float*)d_in[8];
  const float* wout = (const float*)d_in[9];

  u32* wxT = (u32*)d_ws;            // 512*64*4 = 128 KB
  u32* whT = wxT + NC * 64;         // +128 KB

  (void)hipFuncSetAttribute((const void*)lstm_fused,
                            hipFuncAttributeMaxDynamicSharedMemorySize, LDS_TOTAL);

  pack_w<<<64, 512, 0, stream>>>(x2i, x2f, x2g, x2o, h2i, h2f, h2g, h2o, wxT, whT);
  lstm_fused<<<NBATCH, 512, LDS_TOTAL, stream>>>(x, wxT, whT, wout, (float*)d_out);
}

// Round 5
// 288.746 us; speedup vs baseline: 1.1151x; 1.1151x over previous
//
#include <hip/hip_runtime.h>

typedef unsigned int u32;
typedef __fp16 half2_t __attribute__((ext_vector_type(2)));
typedef __fp16 half8_t __attribute__((ext_vector_type(8)));
typedef float  f32x4   __attribute__((ext_vector_type(4)));

#define DIN 128
#define DH  128
#define SEQL 512
#define NBATCH 256
#define NC  512          // 4*DH fused gate columns
#define TC  64           // timesteps per chunk
#define NCHUNK (SEQL/TC) // 8

#define LDS_HOFF 65536   // hbuf byte offset (xgT = 64 KB below it)
#define LDS_TOTAL (65536 + 512)

__device__ __forceinline__ u32 pk2(float a, float b) {
  half2_t h = __builtin_amdgcn_cvt_pkrtz(a, b);
  return __builtin_bit_cast(u32, h);
}

__device__ __forceinline__ float fexp2(float x) {
#if defined(__has_builtin) && __has_builtin(__builtin_amdgcn_exp2f)
  return __builtin_amdgcn_exp2f(x);
#else
  return __builtin_exp2f(x);
#endif
}

#define MF(A, B, C) __builtin_amdgcn_mfma_f32_16x16x32_f16( \
    __builtin_bit_cast(half8_t, A), __builtin_bit_cast(half8_t, B), C, 0, 0, 0)

// Pack fused weight matrices into f16-pair (k-pair) column-major images:
// wT[j][kk] = (w[2kk][j], w[2kk+1][j]),  j in [0,512), kk in [0,64)
__global__ void pack_w(const float* __restrict__ x2i, const float* __restrict__ x2f,
                       const float* __restrict__ x2g, const float* __restrict__ x2o,
                       const float* __restrict__ h2i, const float* __restrict__ h2f,
                       const float* __restrict__ h2g, const float* __restrict__ h2o,
                       u32* __restrict__ wxT, u32* __restrict__ whT) {
  int idx = blockIdx.x * blockDim.x + threadIdx.x;   // 0..32767
  if (idx >= NC * 64) return;
  int j = idx >> 6, kk = idx & 63;
  int g = j >> 7, jjj = j & 127;
  const float* wx = (g == 0) ? x2i : (g == 1) ? x2f : (g == 2) ? x2g : x2o;
  const float* wh = (g == 0) ? h2i : (g == 1) ? h2f : (g == 2) ? h2g : h2o;
  wxT[idx] = pk2(wx[(2*kk)*DH + jjj], wx[(2*kk+1)*DH + jjj]);
  whT[idx] = pk2(wh[(2*kk)*DH + jjj], wh[(2*kk+1)*DH + jjj]);
}

// LDS: xgT [512 col][128 B of t, XOR-swizzled f16] = 64 KB ; hbuf [2][128] f16
__global__ __launch_bounds__(512, 2)
void lstm_fused(
    const float* __restrict__ x, const u32* __restrict__ wxT,
    const u32* __restrict__ whT, const float* __restrict__ w_out,
    float* __restrict__ out) {
  extern __shared__ char lds[];
  char* xgT = lds;

  const int tid = threadIdx.x;
  const int b   = blockIdx.x;
  const int l   = tid & 63, wv = tid >> 6;
  const int kg  = l >> 4, r15 = l & 15;

  // Persistent recurrence B-frags: wave wv owns n-tiles {wv, 8+wv, 16+wv, 24+wv}
  // i.e. cols g*128 + [16wv, 16wv+16) for each gate g. bw[g][kt] per k-tile.
  // Same fragment addressing as phase A's wxT B-frags (proven correct).
  uint4 bw[4][4];
#pragma unroll
  for (int g = 0; g < 4; ++g) {
    const uint4* wp = (const uint4*)(whT + (g * DH + wv * 16 + r15) * 64);
#pragma unroll
    for (int kt = 0; kt < 4; ++kt) bw[g][kt] = wp[kt * 4 + kg];
  }

  if (tid < 128) ((u32*)(lds + LDS_HOFF))[tid] = 0u;   // zero both h buffers
  float c = 0.f;
  u32 rdh = LDS_HOFF;          // current h (f16[128])
  u32 wrh = LDS_HOFF + 256;    // next h
  const float* xb = x + (size_t)b * SEQL * DIN;
  __syncthreads();

  for (int ch = 0; ch < NCHUNK; ++ch) {
    // ---- phase A: xg[t][col] = x_chunk @ wx via MFMA, A-frags from global ----
#pragma unroll 1
    for (int tt = 0; tt < 4; ++tt) {
      uint4 afr[4];
#pragma unroll
      for (int ko = 0; ko < 4; ++ko) {
        const float4* xp = (const float4*)(xb + (size_t)(ch*TC + tt*16 + r15)*DIN + ko*32 + kg*8);
        float4 v0 = xp[0], v1 = xp[1];
        afr[ko].x = pk2(v0.x, v0.y); afr[ko].y = pk2(v0.z, v0.w);
        afr[ko].z = pk2(v1.x, v1.y); afr[ko].w = pk2(v1.z, v1.w);
      }
#pragma unroll
      for (int nt = 0; nt < 4; ++nt) {
        int n = wv * 64 + nt * 16 + r15;
        f32x4 acc = {0.f, 0.f, 0.f, 0.f};
#pragma unroll
        for (int ko = 0; ko < 4; ++ko) {
          uint4 bf = *(const uint4*)(wxT + n*64 + ko*16 + kg*4);
          acc = MF(afr[ko], bf, acc);
        }
        // store C: col n, t0 = tt*16+kg*4 .. +4, into [col][t] XOR-swizzled
        int t0 = tt*16 + kg*4;
        u32 off = (u32)(n*128 + ((t0*2) ^ ((n & 7) << 4)));
        uint2 pw; pw.x = pk2(acc[0], acc[1]); pw.y = pk2(acc[2], acc[3]);
        *(uint2*)(xgT + off) = pw;
      }
    }
    __syncthreads();

    // ---- phase B: 64 sequential steps, MFMA recurrence (M=1 padded to 16) ----
#pragma unroll 1
    for (int m = 0; m < 8; ++m) {
      // xg for this wave's cols, timesteps [8m, 8m+8): one b128 per gate
      half8_t xh[4];
#pragma unroll
      for (int g = 0; g < 4; ++g) {
        int cg = g * DH + wv * 16 + r15;
        xh[g] = __builtin_bit_cast(half8_t,
            *(const uint4*)(xgT + cg*128 + ((m*16) ^ ((cg & 7) << 4))));
      }
#pragma unroll
      for (int s8 = 0; s8 < 8; ++s8) {
        // A-frags: all 16 "rows" = h (broadcast); lane needs h[kt*32+kg*8 .. +8]
        uint4 a0 = *(const uint4*)(lds + rdh +   0 + kg*16);
        uint4 a1 = *(const uint4*)(lds + rdh +  64 + kg*16);
        uint4 a2 = *(const uint4*)(lds + rdh + 128 + kg*16);
        uint4 a3 = *(const uint4*)(lds + rdh + 192 + kg*16);
        f32x4 z = {0.f, 0.f, 0.f, 0.f};
        f32x4 aci = z, acf = z, acg = z, aco = z;
        aci = MF(a0, bw[0][0], aci); acf = MF(a0, bw[1][0], acf);
        acg = MF(a0, bw[2][0], acg); aco = MF(a0, bw[3][0], aco);
        aci = MF(a1, bw[0][1], aci); acf = MF(a1, bw[1][1], acf);
        acg = MF(a1, bw[2][1], acg); aco = MF(a1, bw[3][1], aco);
        aci = MF(a2, bw[0][2], aci); acf = MF(a2, bw[1][2], acf);
        acg = MF(a2, bw[2][2], acg); aco = MF(a2, bw[3][2], aco);
        aci = MF(a3, bw[0][3], aci); acf = MF(a3, bw[1][3], acf);
        acg = MF(a3, bw[2][3], acg); aco = MF(a3, bw[3][3], aco);
        // all C rows identical (A rows identical) -> reg 0 holds gate[col]
        float gi = aci[0] + (float)xh[0][s8];
        float gf = acf[0] + (float)xh[1][s8];
        float gg = acg[0] + (float)xh[2][s8];
        float go = aco[0] + (float)xh[3][s8];
        float si = __builtin_amdgcn_rcpf(1.f + fexp2(gi * -1.442695041f));
        float sf = __builtin_amdgcn_rcpf(1.f + fexp2(gf * -1.442695041f));
        float sg = __builtin_fmaf(2.f,
                     __builtin_amdgcn_rcpf(1.f + fexp2(gg * -2.885390082f)), -1.f);
        float so = __builtin_amdgcn_rcpf(1.f + fexp2(go * -1.442695041f));
        c = __builtin_fmaf(sf, c, si * sg);
        float th = __builtin_fmaf(2.f,
                     __builtin_amdgcn_rcpf(1.f + fexp2(c * -2.885390082f)), -1.f);
        float hval = so * th;
        if (l < 16) *(__fp16*)(lds + wrh + (wv * 16 + l) * 2) = (__fp16)hval;
        u32 tswap = rdh; rdh = wrh; wrh = tswap;
        __syncthreads();
      }
    }
  }

  // ---- tail: out[b][n] = h_final @ w_out ----
  if (tid < DH) {
    int n = tid;
    const u32* hf = (const u32*)(lds + rdh);   // final h (f16 pairs)
    float acc = 0.f;
#pragma unroll 8
    for (int kk = 0; kk < 64; ++kk) {
      half2_t h2v = __builtin_bit_cast(half2_t, hf[kk]);
      acc = __builtin_fmaf((float)h2v[0], w_out[(2*kk)*DH + n],
            __builtin_fmaf((float)h2v[1], w_out[(2*kk+1)*DH + n], acc));
    }
    out[b * DH + n] = acc;
  }
}

extern "C" void kernel_launch(void* const* d_in, const int* in_sizes, int n_in,
                              void* d_out, int out_size, void* d_ws, size_t ws_size,
                              hipStream_t stream) {
  const float* x    = (const float*)d_in[0];
  const float* x2i  = (const float*)d_in[1];
  const float* x2f  = (const float*)d_in[2];
  const float* x2g  = (const float*)d_in[3];
  const float* x2o  = (const float*)d_in[4];
  const float* h2i  = (const float*)d_in[5];
  const float* h2f  = (const float*)d_in[6];
  const float* h2g  = (const float*)d_in[7];
  const float* h2o  = (const float*)d_in[8];
  const float* wout = (const float*)d_in[9];

  u32* wxT = (u32*)d_ws;            // 512*64*4 = 128 KB
  u32* whT = wxT + NC * 64;         // +128 KB

  (void)hipFuncSetAttribute((const void*)lstm_fused,
                            hipFuncAttributeMaxDynamicSharedMemorySize, LDS_TOTAL);

  pack_w<<<64, 512, 0, stream>>>(x2i, x2f, x2g, x2o, h2i, h2f, h2g, h2o, wxT, whT);
  lstm_fused<<<NBATCH, 512, LDS_TOTAL, stream>>>(x, wxT, whT, wout, (float*)d_out);
}